// Round 3
// baseline (327.257 us; speedup 1.0000x reference)
//
#include <hip/hip_runtime.h>
#include <math.h>

#define HW   25600   // 160*160
#define WID  160
#define NPAR 91
#define TOPK 32

// workspace layout (float-element offsets into d_ws)
#define CV_OFF 0        // cand values [16][800]
#define CI_OFF 12800    // cand indices [16][800] (int)
#define TV_OFF 25600    // top values  [16][32]
#define TI_OFF 26112    // top indices [16][32] (int)

// ---------------- K1: peak detect + exact per-chunk top-32 (rank select) ----------------
// Chunk = 1024 contiguous pixels. Candidate set = peaks ∪ first-32 pixels of the chunk:
// provably contains the chunk's true top-32 under (value desc, index asc). Ranks are
// unique (distinct (v,i) pairs) -> slots 0..31 written exactly once.
__global__ __launch_bounds__(256) void k1_peaks(const float* __restrict__ hms,
                                                float* __restrict__ wsf,
                                                int* __restrict__ wsi)
{
  const int chunk = blockIdx.x;   // 0..24
  const int b     = blockIdx.y;   // 0..15
  const int tid   = threadIdx.x;
  const float* hb = hms + (size_t)b * HW;

  __shared__ float cv[1056];
  __shared__ int   ci[1056];
  __shared__ int   cnt;
  if (tid == 0) cnt = 0;
  __syncthreads();

  const int base = chunk << 10;
  #pragma unroll
  for (int k = 0; k < 4; ++k) {
    int lp = tid + (k << 8);
    int p  = base + lp;
    int y  = p / WID, x = p - y * WID;
    float c = hb[p];
    bool peak = true;
    #pragma unroll
    for (int dy = -1; dy <= 1; ++dy) {
      #pragma unroll
      for (int dx = -1; dx <= 1; ++dx) {
        if (dy == 0 && dx == 0) continue;
        int yy = y + dy, xx = x + dx;
        if (yy < 0 || yy >= WID || xx < 0 || xx >= WID) continue;
        if (hb[yy * WID + xx] > c) peak = false;
      }
    }
    if (peak || lp < 32) {
      int slot = atomicAdd(&cnt, 1);
      cv[slot] = peak ? c : 0.0f;
      ci[slot] = p;
    }
  }
  __syncthreads();

  const int P = cnt;              // >= 32 always
  float* outv = wsf + CV_OFF + b * 800 + chunk * 32;
  int*   outi = wsi + CI_OFF + b * 800 + chunk * 32;
  for (int j = tid; j < P; j += 256) {
    float vj = cv[j]; int ij = ci[j];
    int rank = 0;
    for (int m = 0; m < P; ++m) {
      float vm = cv[m]; int im = ci[m];
      rank += (vm > vj || (vm == vj && im < ij)) ? 1 : 0;
    }
    if (rank < TOPK) { outv[rank] = vj; outi[rank] = ij; }
  }
}

// ---------------- K2: exact per-image top-32 of the 800 chunk candidates ----------------
__global__ __launch_bounds__(256) void k2_topk(float* __restrict__ wsf,
                                               int* __restrict__ wsi)
{
  const int seg = blockIdx.x;     // 0..3 -> candidates [seg*200, seg*200+200)
  const int b   = blockIdx.y;
  const int tid = threadIdx.x;

  __shared__ float cv[800];
  __shared__ int   ci[800];
  const float* inv = wsf + CV_OFF + b * 800;
  const int*   ini = wsi + CI_OFF + b * 800;
  for (int j = tid; j < 800; j += 256) { cv[j] = inv[j]; ci[j] = ini[j]; }
  __syncthreads();

  if (tid < 200) {
    int j = seg * 200 + tid;
    float vj = cv[j]; int ij = ci[j];
    int rank = 0;
    for (int m = 0; m < 800; ++m) {
      float vm = cv[m]; int im = ci[m];
      rank += (vm > vj || (vm == vj && im < ij)) ? 1 : 0;
    }
    if (rank < TOPK) {
      wsf[TV_OFF + b * TOPK + rank] = vj;
      wsi[TI_OFF + b * TOPK + rank] = ij;
    }
  }
}

// ---------------- K3: per-image verts + landmarks + bbox + pose + NMS + outputs --------
__global__ __launch_bounds__(1024) void k3_tail(const float* __restrict__ pmaps,
                                                const float* __restrict__ oshapes,
                                                const float* __restrict__ pms,
                                                const float* __restrict__ ub,
                                                const float* __restrict__ sb,
                                                const float* __restrict__ eb,
                                                const float* __restrict__ wsf,
                                                const int* __restrict__ wsi,
                                                float* __restrict__ out)
{
  const int b   = blockIdx.x;
  const int tid = threadIdx.x;

  __shared__ float s_sb[10200];        // 204 x 50
  __shared__ float s_eb[5916];         // 204 x 29
  __shared__ float s_ub[204];
  __shared__ float s_prm[TOPK][NPAR];
  __shared__ float s_lnm[TOPK * 136];
  __shared__ float s_bbox[TOPK][5];
  __shared__ float s_pose[TOPK][3];
  __shared__ float s_topv[TOPK];
  __shared__ int   s_ti[TOPK];
  __shared__ float s_obox[TOPK][4];
  __shared__ float s_osc[TOPK];
  __shared__ int   s_dv[TOPK];
  __shared__ int   s_match[TOPK];

  // stage bases into LDS once per image
  {
    const float4* s4 = (const float4*)sb;
    float4* d4 = (float4*)s_sb;
    for (int i = tid; i < 2550; i += 1024) d4[i] = s4[i];
    const float4* e4 = (const float4*)eb;
    float4* de = (float4*)s_eb;
    for (int i = tid; i < 1479; i += 1024) de[i] = e4[i];
    if (tid < 51) ((float4*)s_ub)[tid] = ((const float4*)ub)[tid];
  }
  if (tid < TOPK) {
    s_topv[tid] = wsf[TV_OFF + b * TOPK + tid];
    s_ti[tid]   = wsi[TI_OFF + b * TOPK + tid];
  }
  __syncthreads();

  // gather + denormalize params
  for (int j = tid; j < TOPK * NPAR; j += 1024) {
    int n = j / NPAR, q = j - n * NPAR;
    int p = s_ti[n];
    s_prm[n][q] = pmaps[((size_t)b * HW + p) * NPAR + q] * pms[NPAR + q] + pms[q];
  }
  __syncthreads();

  // verts, landmarks, bbox, pose — (n = det, l = lane-in-32)
  {
    const int n = tid >> 5, l = tid & 31;
    const float* prm = s_prm[n];
    float s   = prm[0];
    float R00 = prm[1], R01 = prm[2],  R02 = prm[3];
    float R10 = prm[5], R11 = prm[6],  R12 = prm[7];
    int p  = s_ti[n];
    int ys = p / WID, xs = p - ys * WID;
    float rr0 = oshapes[2 * b]     / 160.0f;
    float rr1 = oshapes[2 * b + 1] / 160.0f;
    float coy = (float)ys * rr0;
    float cox = (float)xs * rr1;

    float mny = INFINITY, mnx = INFINITY, mxy = -INFINITY, mxx = -INFINITY;
    for (int vv = l; vv < 68; vv += 32) {
      float a0 = s_ub[3 * vv], a1 = s_ub[3 * vv + 1], a2 = s_ub[3 * vv + 2];
      const float* sr = s_sb + 3 * vv * 50;
      for (int q = 0; q < 50; ++q) {
        float w = prm[12 + q];
        a0 += sr[q] * w; a1 += sr[50 + q] * w; a2 += sr[100 + q] * w;
      }
      const float* er = s_eb + 3 * vv * 29;
      for (int q = 0; q < 29; ++q) {
        float w = prm[62 + q];
        a0 += er[q] * w; a1 += er[29 + q] * w; a2 += er[58 + q] * w;
      }
      float l0 = s * (a0 * R00 + a1 * R01 + a2 * R02);
      float l1 = s * (a0 * R10 + a1 * R11 + a2 * R12);
      float py = l1 + coy;
      float px = l0 + cox;
      s_lnm[n * 136 + vv * 2]     = py;
      s_lnm[n * 136 + vv * 2 + 1] = px;
      mny = fminf(mny, py); mnx = fminf(mnx, px);
      mxy = fmaxf(mxy, py); mxx = fmaxf(mxx, px);
    }
    #pragma unroll
    for (int off = 16; off > 0; off >>= 1) {
      mny = fminf(mny, __shfl_xor(mny, off));
      mnx = fminf(mnx, __shfl_xor(mnx, off));
      mxy = fmaxf(mxy, __shfl_xor(mxy, off));
      mxx = fmaxf(mxx, __shfl_xor(mxx, off));
    }
    if (l == 0) {
      float sc = s_topv[n];
      bool mask = sc > 0.5f;
      s_bbox[n][0] = mask ? mny : -1.0f;
      s_bbox[n][1] = mask ? mnx : -1.0f;
      s_bbox[n][2] = mask ? mxy : -1.0f;
      s_bbox[n][3] = mask ? mxx : -1.0f;
      s_bbox[n][4] = mask ? sc  : -1.0f;
      float R20 = prm[9], R21 = prm[10], R22 = prm[11];
      const float R2D = 57.29577951308232f;
      float yaw = asinf(-R20) * R2D;
      float cyw = cosf(yaw);                       // degrees into cos, as ref does
      float pitch = atan2f(R21 / cyw, R22 / cyw) * R2D;
      float roll  = atan2f(R10 / cyw, R00 / cyw) * R2D;
      s_pose[n][0] = pitch; s_pose[n][1] = yaw; s_pose[n][2] = roll;
    }
  }
  __syncthreads();

  // NMS (traversal order == identity: scores descending, masked -1 rows form suffix)
  if (tid < 64) {
    int j = tid;
    float b0 = 0.f, b1 = 0.f, b2 = 0.f, b3 = 0.f, sc = -1e30f;
    if (j < TOPK) {
      b0 = s_bbox[j][0]; b1 = s_bbox[j][1]; b2 = s_bbox[j][2]; b3 = s_bbox[j][3];
      sc = s_bbox[j][4];
    }
    float area = (b2 - b0) * (b3 - b1);
    int supp = (j >= TOPK) ? 1 : 0;
    for (int i = 0; i < TOPK; ++i) {
      float i0 = __shfl(b0, i), i1 = __shfl(b1, i);
      float i2 = __shfl(b2, i), i3 = __shfl(b3, i);
      float ia = __shfl(area, i);
      int isup = __shfl(supp, i);
      if (!isup && j > i && j < TOPK) {
        float yy1 = fmaxf(b0, i0), xx1 = fmaxf(b1, i1);
        float yy2 = fminf(b2, i2), xx2 = fminf(b3, i3);
        float inter = fmaxf(yy2 - yy1, 0.0f) * fmaxf(xx2 - xx1, 0.0f);
        float uni = area + ia - inter;
        float iou = inter / fmaxf(uni, 1e-8f);
        if (iou > 0.4f) supp = 1;
      }
    }
    bool keep = (j < TOPK) && !supp;
    unsigned long long km = __ballot(keep);
    int rank = __popcll(km & ((1ull << j) - 1ull));
    if (j < TOPK) {
      s_obox[j][0] = 0.f; s_obox[j][1] = 0.f; s_obox[j][2] = 0.f; s_obox[j][3] = 0.f;
      s_osc[j] = 0.f;
    }
    if (keep) {
      s_obox[rank][0] = b0; s_obox[rank][1] = b1;
      s_obox[rank][2] = b2; s_obox[rank][3] = b3;
      s_osc[rank] = sc;
    }
  }
  __syncthreads();

  if (tid < TOPK) {
    int dv = 1;
    #pragma unroll
    for (int c = 0; c < 4; ++c) {
      float t = s_obox[tid][c];
      if (t == -1.0f || t == 0.0f) { t = INFINITY; dv = 0; }  // -1 -> inf, 0 -> inf
      s_obox[tid][c] = t;
    }
    s_dv[tid] = dv;
  }
  __syncthreads();

  if (tid < TOPK) {
    float mysc = s_topv[tid];
    int m = 0;
    for (int sl = 0; sl < TOPK; ++sl)
      if (s_dv[sl] && s_osc[sl] == mysc) m = 1;   // literal ref 'matched' semantics
    s_match[tid] = m;
  }
  __syncthreads();

  // outputs
  {
    float* outb = out + (size_t)b * 192;                 // (B,32,6)
    for (int j = tid; j < 192; j += 1024) {
      int sl = j / 6, c = j - 6 * sl;
      float val;
      if (c < 4)       val = s_obox[sl][c];
      else if (c == 4) val = s_osc[sl];
      else             val = 0.0f;
      outb[j] = val;
    }
    float* outl = out + 3072 + (size_t)b * 4352;         // (B,32,68,2)
    for (int j = tid; j < 4352; j += 1024) {
      int n = j / 136;
      float t = s_lnm[j];
      outl[j] = s_match[n] ? ((t == -1.0f) ? INFINITY : t) : INFINITY;
    }
    float* outp = out + 72704 + (size_t)b * 96;          // (B,32,3)
    for (int j = tid; j < 96; j += 1024) {
      int n = j / 3;
      float t = s_pose[n][j - 3 * n];
      outp[j] = s_match[n] ? ((t == -1.0f) ? INFINITY : t) : INFINITY;
    }
  }
}

extern "C" void kernel_launch(void* const* d_in, const int* in_sizes, int n_in,
                              void* d_out, int out_size, void* d_ws, size_t ws_size,
                              hipStream_t stream) {
  const float* hms   = (const float*)d_in[0];
  const float* pmaps = (const float*)d_in[1];
  const float* osh   = (const float*)d_in[2];
  const float* pms   = (const float*)d_in[3];
  const float* ub    = (const float*)d_in[4];
  const float* sb    = (const float*)d_in[5];
  const float* eb    = (const float*)d_in[6];
  float* o   = (float*)d_out;
  float* wsf = (float*)d_ws;
  int*   wsi = (int*)d_ws;

  k1_peaks<<<dim3(25, 16), 256, 0, stream>>>(hms, wsf, wsi);
  k2_topk <<<dim3(4, 16),  256, 0, stream>>>(wsf, wsi);
  k3_tail <<<16, 1024, 0, stream>>>(pmaps, osh, pms, ub, sb, eb, wsf, wsi, o);
}

// Round 5
// 241.256 us; speedup vs baseline: 1.3565x; 1.3565x over previous
//
#include <hip/hip_runtime.h>
#include <math.h>

#define HW   25600   // 160*160
#define WID  160
#define NPAR 91
#define TOPK 32
#define NCH  20      // 8-row chunks per image
#define NCAND (NCH*TOPK)   // 640 candidates per image

// workspace layout (float-element offsets into d_ws)
#define CV_OFF 0        // cand values  [16][640]
#define CI_OFF 10240    // cand indices [16][640] (int)
#define TV_OFF 20480    // top values   [16][32]
#define TI_OFF 20992    // top indices  [16][32] (int)
#define BB_OFF 21504    // bboxes [16][32][5]
#define PS_OFF 24064    // pose   [16][32][3]
#define LN_OFF 25600    // lnmks  [16][32][136]
// total = 95232 floats = 380928 bytes

// ---------------- K1: LDS-tiled peak detect + exact per-chunk top-32 ----------------
// Chunk = 8 rows (1280 px). Candidate set = peaks ∪ first-32 px of chunk: provably
// contains the chunk's true top-32 under (value desc, index asc) — non-peaks are 0,
// and the z lowest-index zeros (z = 32 - #peaks) lie within the first 32 px since
// those contain >= z non-peaks. Ranks unique (distinct (v,i)) -> slots 0..31 each
// written exactly once. Candidate insertion order is irrelevant (rank-select).
__global__ __launch_bounds__(256) void k1_peaks(const float* __restrict__ hms,
                                                float* __restrict__ wsf,
                                                int* __restrict__ wsi)
{
  const int chunk = blockIdx.x;   // 0..19 -> rows [8c, 8c+8)
  const int b     = blockIdx.y;   // 0..15
  const int tid   = threadIdx.x;
  const float* hb = hms + (size_t)b * HW;

  __shared__ float tile[10 * 160];   // rows 8c-1 .. 8c+8
  __shared__ float cv[384];          // max peaks (independent) 320 + 32
  __shared__ int   ci[384];
  __shared__ int   cnt;
  if (tid == 0) cnt = 0;

  // BUGFIX r4: 400 float4 groups but only 256 threads — must loop.
  for (int i = tid; i < 400; i += 256) {
    int r = i / 40, g = i - 40 * r;         // r 0..9, g 0..39 (float4 groups)
    int gr = chunk * 8 - 1 + r;
    float4 val;
    if (gr < 0 || gr >= 160) val = make_float4(-INFINITY, -INFINITY, -INFINITY, -INFINITY);
    else                     val = *(const float4*)(hb + gr * WID + g * 4);
    *(float4*)(tile + r * 160 + g * 4) = val;
  }
  __syncthreads();

  #pragma unroll
  for (int k = 0; k < 5; ++k) {
    int lp = tid + (k << 8);                // 0..1279 chunk-local
    int y  = lp / 160, x = lp - y * 160;    // y 0..7
    int ty = y + 1;
    float c = tile[ty * 160 + x];
    bool peak = true;
    if (x > 0) {
      if (tile[(ty - 1) * 160 + x - 1] > c) peak = false;
      if (tile[ ty      * 160 + x - 1] > c) peak = false;
      if (tile[(ty + 1) * 160 + x - 1] > c) peak = false;
    }
    if (tile[(ty - 1) * 160 + x] > c) peak = false;
    if (tile[(ty + 1) * 160 + x] > c) peak = false;
    if (x < 159) {
      if (tile[(ty - 1) * 160 + x + 1] > c) peak = false;
      if (tile[ ty      * 160 + x + 1] > c) peak = false;
      if (tile[(ty + 1) * 160 + x + 1] > c) peak = false;
    }
    if (peak || lp < 32) {
      int slot = atomicAdd(&cnt, 1);
      cv[slot] = peak ? c : 0.0f;
      ci[slot] = chunk * 1280 + lp;         // global pixel index
    }
  }
  __syncthreads();

  const int P = cnt;                        // >= 32 always
  float* outv = wsf + CV_OFF + b * NCAND + chunk * TOPK;
  int*   outi = wsi + CI_OFF + b * NCAND + chunk * TOPK;
  for (int j = tid; j < P; j += 256) {
    float vj = cv[j]; int ij = ci[j];
    int rank = 0;
    for (int m = 0; m < P; ++m) {
      float vm = cv[m]; int im = ci[m];
      rank += (vm > vj || (vm == vj && im < ij)) ? 1 : 0;
    }
    if (rank < TOPK) { outv[rank] = vj; outi[rank] = ij; }
  }
}

// ---------------- K2: exact per-image top-32 of the 640 chunk candidates ----------------
__global__ __launch_bounds__(256) void k2_topk(float* __restrict__ wsf,
                                               int* __restrict__ wsi)
{
  const int seg = blockIdx.x;     // 0..3 -> candidates [seg*160, seg*160+160)
  const int b   = blockIdx.y;
  const int tid = threadIdx.x;

  __shared__ float cv[NCAND];
  __shared__ int   ci[NCAND];
  const float* inv = wsf + CV_OFF + b * NCAND;
  const int*   ini = wsi + CI_OFF + b * NCAND;
  for (int j = tid; j < NCAND; j += 256) { cv[j] = inv[j]; ci[j] = ini[j]; }
  __syncthreads();

  if (tid < 160) {
    int j = seg * 160 + tid;
    float vj = cv[j]; int ij = ci[j];
    int rank = 0;
    for (int m = 0; m < NCAND; ++m) {
      float vm = cv[m]; int im = ci[m];
      rank += (vm > vj || (vm == vj && im < ij)) ? 1 : 0;
    }
    if (rank < TOPK) {
      wsf[TV_OFF + b * TOPK + rank] = vj;
      wsi[TI_OFF + b * TOPK + rank] = ij;
    }
  }
}

// ---------------- K3: per-detection 3DMM verts, landmarks, bbox, pose ----------------
__global__ __launch_bounds__(256) void k3_verts(const float* __restrict__ pmaps,
                                                const float* __restrict__ oshapes,
                                                const float* __restrict__ pms,
                                                const float* __restrict__ ub,
                                                const float* __restrict__ sb,
                                                const float* __restrict__ eb,
                                                float* __restrict__ wsf,
                                                const int* __restrict__ wsi)
{
  const int n   = blockIdx.x;     // 0..31 detection slot
  const int b   = blockIdx.y;     // image
  const int tid = threadIdx.x;

  __shared__ float s_sb[10200];   // 204 x 50
  __shared__ float s_eb[5916];    // 204 x 29
  __shared__ float s_ub[204];
  __shared__ float s_prm[NPAR];
  __shared__ float s_v[204];
  __shared__ float s_pyx[136];

  {
    const float4* s4 = (const float4*)sb;
    float4* d4 = (float4*)s_sb;
    for (int i = tid; i < 2550; i += 256) d4[i] = s4[i];
    const float4* e4 = (const float4*)eb;
    float4* de = (float4*)s_eb;
    for (int i = tid; i < 1479; i += 256) de[i] = e4[i];
    if (tid < 51) ((float4*)s_ub)[tid] = ((const float4*)ub)[tid];
  }
  const int p = wsi[TI_OFF + b * TOPK + n];
  if (tid < NPAR)
    s_prm[tid] = pmaps[((size_t)b * HW + p) * NPAR + tid] * pms[NPAR + tid] + pms[tid];
  __syncthreads();

  // v[r] = ub[r] + S[r,:]·shp + E[r,:]·exp  (sequential q order == ref einsum order)
  if (tid < 204) {
    float acc = s_ub[tid];
    const float* srow = s_sb + tid * 50;
    for (int q = 0; q < 50; ++q) acc += srow[q] * s_prm[12 + q];
    const float* erow = s_eb + tid * 29;
    for (int q = 0; q < 29; ++q) acc += erow[q] * s_prm[62 + q];
    s_v[tid] = acc;
  }
  __syncthreads();

  const int ys = p / WID, xs = p - (p / WID) * WID;
  if (tid < 68) {
    float a0 = s_v[3 * tid], a1 = s_v[3 * tid + 1], a2 = s_v[3 * tid + 2];
    float s  = s_prm[0];
    float l0 = s * (a0 * s_prm[1] + a1 * s_prm[2] + a2 * s_prm[3]);
    float l1 = s * (a0 * s_prm[5] + a1 * s_prm[6] + a2 * s_prm[7]);
    float rr0 = oshapes[2 * b]     / 160.0f;
    float rr1 = oshapes[2 * b + 1] / 160.0f;
    float py = l1 + (float)ys * rr0;
    float px = l0 + (float)xs * rr1;
    float* ln = wsf + LN_OFF + ((size_t)b * TOPK + n) * 136;
    ln[2 * tid]     = py;
    ln[2 * tid + 1] = px;
    s_pyx[2 * tid]     = py;
    s_pyx[2 * tid + 1] = px;
  }
  __syncthreads();

  if (tid < 64) {
    float py = s_pyx[2 * tid], px = s_pyx[2 * tid + 1];
    float mny = py, mxy = py, mnx = px, mxx = px;
    if (tid < 4) {
      float qy = s_pyx[128 + 2 * tid], qx = s_pyx[129 + 2 * tid];
      mny = fminf(mny, qy); mxy = fmaxf(mxy, qy);
      mnx = fminf(mnx, qx); mxx = fmaxf(mxx, qx);
    }
    #pragma unroll
    for (int off = 32; off > 0; off >>= 1) {
      mny = fminf(mny, __shfl_xor(mny, off));
      mnx = fminf(mnx, __shfl_xor(mnx, off));
      mxy = fmaxf(mxy, __shfl_xor(mxy, off));
      mxx = fmaxf(mxx, __shfl_xor(mxx, off));
    }
    if (tid == 0) {
      float sc = wsf[TV_OFF + b * TOPK + n];
      bool mask = sc > 0.5f;
      float* bb = wsf + BB_OFF + ((size_t)b * TOPK + n) * 5;
      bb[0] = mask ? mny : -1.0f;
      bb[1] = mask ? mnx : -1.0f;
      bb[2] = mask ? mxy : -1.0f;
      bb[3] = mask ? mxx : -1.0f;
      bb[4] = mask ? sc  : -1.0f;
      const float R2D = 57.29577951308232f;
      float R20 = s_prm[9], R21 = s_prm[10], R22 = s_prm[11];
      float yaw = asinf(-R20) * R2D;
      float cyw = cosf(yaw);                        // degrees into cos, as the ref does
      float pitch = atan2f(R21 / cyw, R22 / cyw) * R2D;
      float roll  = atan2f(s_prm[5] / cyw, s_prm[1] / cyw) * R2D;
      float* ps = wsf + PS_OFF + ((size_t)b * TOPK + n) * 3;
      ps[0] = pitch; ps[1] = yaw; ps[2] = roll;
    }
  }
}

// ---------------- K4: NMS + matched + output writes ----------------
__global__ __launch_bounds__(256) void k4_nms(const float* __restrict__ wsf,
                                              float* __restrict__ out)
{
  const int b   = blockIdx.x;
  const int tid = threadIdx.x;

  __shared__ float s_bbox[TOPK][5];
  __shared__ float s_topv[TOPK];
  __shared__ float s_obox[TOPK][4];
  __shared__ float s_osc[TOPK];
  __shared__ int   s_dv[TOPK];
  __shared__ int   s_match[TOPK];

  if (tid < 160) ((float*)s_bbox)[tid] = wsf[BB_OFF + b * 160 + tid];
  if (tid < TOPK) s_topv[tid] = wsf[TV_OFF + b * TOPK + tid];
  __syncthreads();

  // NMS: traversal order == identity (scores descending, masked -1 rows form suffix)
  if (tid < 64) {
    int j = tid;
    float b0 = 0.f, b1 = 0.f, b2 = 0.f, b3 = 0.f, sc = -1e30f;
    if (j < TOPK) {
      b0 = s_bbox[j][0]; b1 = s_bbox[j][1]; b2 = s_bbox[j][2]; b3 = s_bbox[j][3];
      sc = s_bbox[j][4];
    }
    float area = (b2 - b0) * (b3 - b1);
    int supp = (j >= TOPK) ? 1 : 0;
    for (int i = 0; i < TOPK; ++i) {
      float i0 = __shfl(b0, i), i1 = __shfl(b1, i);
      float i2 = __shfl(b2, i), i3 = __shfl(b3, i);
      float ia = __shfl(area, i);
      int isup = __shfl(supp, i);
      if (!isup && j > i && j < TOPK) {
        float yy1 = fmaxf(b0, i0), xx1 = fmaxf(b1, i1);
        float yy2 = fminf(b2, i2), xx2 = fminf(b3, i3);
        float inter = fmaxf(yy2 - yy1, 0.0f) * fmaxf(xx2 - xx1, 0.0f);
        float uni = area + ia - inter;
        float iou = inter / fmaxf(uni, 1e-8f);
        if (iou > 0.4f) supp = 1;
      }
    }
    bool keep = (j < TOPK) && !supp;
    unsigned long long km = __ballot(keep);
    int rank = __popcll(km & ((1ull << j) - 1ull));
    if (j < TOPK) {
      s_obox[j][0] = 0.f; s_obox[j][1] = 0.f; s_obox[j][2] = 0.f; s_obox[j][3] = 0.f;
      s_osc[j] = 0.f;
    }
    if (keep) {
      s_obox[rank][0] = b0; s_obox[rank][1] = b1;
      s_obox[rank][2] = b2; s_obox[rank][3] = b3;
      s_osc[rank] = sc;
    }
  }
  __syncthreads();

  if (tid < TOPK) {
    int dv = 1;
    #pragma unroll
    for (int c = 0; c < 4; ++c) {
      float t = s_obox[tid][c];
      if (t == -1.0f || t == 0.0f) { t = INFINITY; dv = 0; }  // -1 -> inf, 0 -> inf
      s_obox[tid][c] = t;
    }
    s_dv[tid] = dv;
  }
  __syncthreads();

  if (tid < TOPK) {
    float mysc = s_topv[tid];
    int m = 0;
    for (int sl = 0; sl < TOPK; ++sl)
      if (s_dv[sl] && s_osc[sl] == mysc) m = 1;   // literal ref 'matched' semantics
    s_match[tid] = m;
  }
  __syncthreads();

  {
    float* outb = out + (size_t)b * 192;                  // (B,32,6)
    for (int j = tid; j < 192; j += 256) {
      int sl = j / 6, c = j - 6 * sl;
      float val;
      if (c < 4)       val = s_obox[sl][c];
      else if (c == 4) val = s_osc[sl];
      else             val = 0.0f;
      outb[j] = val;
    }
    const float* lnw = wsf + LN_OFF + (size_t)b * (TOPK * 136);
    float* outl = out + 3072 + (size_t)b * 4352;          // (B,32,68,2)
    for (int j = tid; j < 4352; j += 256) {
      int n = j / 136;
      float t = lnw[j];
      outl[j] = s_match[n] ? ((t == -1.0f) ? INFINITY : t) : INFINITY;
    }
    const float* psw = wsf + PS_OFF + (size_t)b * (TOPK * 3);
    float* outp = out + 72704 + (size_t)b * 96;           // (B,32,3)
    for (int j = tid; j < 96; j += 256) {
      int n = j / 3;
      float t = psw[j];
      outp[j] = s_match[n] ? ((t == -1.0f) ? INFINITY : t) : INFINITY;
    }
  }
}

extern "C" void kernel_launch(void* const* d_in, const int* in_sizes, int n_in,
                              void* d_out, int out_size, void* d_ws, size_t ws_size,
                              hipStream_t stream) {
  const float* hms   = (const float*)d_in[0];
  const float* pmaps = (const float*)d_in[1];
  const float* osh   = (const float*)d_in[2];
  const float* pms   = (const float*)d_in[3];
  const float* ub    = (const float*)d_in[4];
  const float* sb    = (const float*)d_in[5];
  const float* eb    = (const float*)d_in[6];
  float* o   = (float*)d_out;
  float* wsf = (float*)d_ws;
  int*   wsi = (int*)d_ws;

  k1_peaks<<<dim3(NCH, 16), 256, 0, stream>>>(hms, wsf, wsi);
  k2_topk <<<dim3(4, 16),  256, 0, stream>>>(wsf, wsi);
  k3_verts<<<dim3(32, 16), 256, 0, stream>>>(pmaps, osh, pms, ub, sb, eb, wsf, wsi);
  k4_nms  <<<16,           256, 0, stream>>>(wsf, o);
}